// Round 21
// baseline (258.518 us; speedup 1.0000x reference)
//
#include <hip/hip_runtime.h>
#include <hip/hip_bf16.h>

typedef __attribute__((ext_vector_type(4))) float f32x4;
typedef __attribute__((ext_vector_type(8))) short short8;

#define XROWS 8195            // 3 guard rows + 8192
#define XBATCH (XROWS * 1024) // elems per padded batch

__device__ __forceinline__ short f2bf(float f) {
    union { __hip_bfloat16 h; short s; } u;
    u.h = __float2bfloat16(f);
    return u.s;
}

__device__ __forceinline__ void async16(const void* g, void* l) {
    __builtin_amdgcn_global_load_lds(
        (const __attribute__((address_space(1))) unsigned int*)g,
        (__attribute__((address_space(3))) unsigned int*)l, 16, 0, 0);
}

// ---------------------------------------------------------------------------
// Fused prepass (R19/R20-verified):
//   blocks 0..2047:    x fp32 [4][8192][1024] -> Xbf bf16 [4][3+8192][1024]
//   blocks 2048..6143: kernels [4096][1024] fp32 -> Kt [1024][4096] bf16
// ---------------------------------------------------------------------------
__global__ void __launch_bounds__(256)
prepass_fused(const float* __restrict__ x, __hip_bfloat16* __restrict__ Xbf,
              const float* __restrict__ kern, __hip_bfloat16* __restrict__ Kt) {
    int blk = blockIdx.x;
    if (blk < 2048) {
        size_t idx = (size_t)blk * 256 + threadIdx.x;
        if (idx < 1536) {  // zero 4*3*1024 guard elems
            int b = (int)(idx / 384);
            int r = (int)(idx % 384);
            *reinterpret_cast<short8*>(&Xbf[(size_t)b * XBATCH + r * 8]) =
                (short8){0, 0, 0, 0, 0, 0, 0, 0};
        }
        const size_t stride = (size_t)2048 * 256;
        const size_t nvec = (size_t)4 * 8192 * 1024 / 8;
        for (size_t v = idx; v < nvec; v += stride) {
            size_t e = v * 8;
            int b = (int)(e >> 23);
            size_t rem = e & ((1u << 23) - 1);
            f32x4 lo = *reinterpret_cast<const f32x4*>(x + e);
            f32x4 hi = *reinterpret_cast<const f32x4*>(x + e + 4);
            short8 pk;
            pk[0] = f2bf(lo[0]); pk[1] = f2bf(lo[1]); pk[2] = f2bf(lo[2]); pk[3] = f2bf(lo[3]);
            pk[4] = f2bf(hi[0]); pk[5] = f2bf(hi[1]); pk[6] = f2bf(hi[2]); pk[7] = f2bf(hi[3]);
            *reinterpret_cast<short8*>(&Xbf[(size_t)b * XBATCH + 3 * 1024 + rem]) = pk;
        }
    } else {
        __shared__ float tile[32][33];
        int b2 = blk - 2048;           // 0..4095
        int k0 = (b2 & 127) << 5;      // 128 k-tiles
        int f0 = (b2 >> 7) << 5;       // 32 f-tiles
        int tx = threadIdx.x & 31;
        int ty = threadIdx.x >> 5;
#pragma unroll
        for (int q = 0; q < 4; q++)
            tile[ty + q * 8][tx] =
                kern[(size_t)(k0 + ty + q * 8) * 1024 + f0 + tx];
        __syncthreads();
#pragma unroll
        for (int q = 0; q < 4; q++)
            Kt[((size_t)(f0 + ty + q * 8) << 12) + k0 + tx] =
                __float2bfloat16(tile[tx][ty + q * 8]);
    }
}

// ---------------------------------------------------------------------------
// Main GEMM — R20 structure with merged stage-free phases (6 barriers per
//   2 K-tiles instead of 8): P2 = (h1,ks0)+(h0,ks1) one barrier, P5 same
//   for buf1. 256^2 tile, BK=64, 8 waves (2M x 4N), wave tile 128x64.
//   Ledger (re-derived): stages P1=A(O.H1) P2=B(O.H1) P3=A(E2.H0)
//   P4=B(E2.H0) P5=A+B(E2.H1) P6=A+B(O2.H0); waits P1=vmcnt(4) (queue 12,
//   drains E's 8), P4=vmcnt(2) (queue 10, drains through B(O.H1)); never
//   0 mid-loop. Race audit: A-HF0 last read in P2 -> staged P3; A-HF1
//   last read P3 -> staged P5; B last read P2/P5 -> staged >=2 barriers
//   later. XOR swizzle (0 conflicts R3-R20); rule-21 DMA; no setprio.
// ---------------------------------------------------------------------------
__global__ void __launch_bounds__(512, 2)
altconv_gemm18(const __hip_bfloat16* __restrict__ Xbf,  // [4][8195][1024]
               const __hip_bfloat16* __restrict__ Kt,   // [1024][4096]
               const float* __restrict__ biases,        // [4][1024]
               float* __restrict__ out) {               // [32768][1024]
    __shared__ alignas(16) __hip_bfloat16 LS[65536];   // 128 KiB

    // bijective XCD swizzle (512 % 8 == 0); nt fastest within an XCD chunk
    int bid  = blockIdx.x;
    int tid2 = (bid & 7) * 64 + (bid >> 3);
    int mt = tid2 >> 2;           // 0..127
    int nt = tid2 & 3;            // 0..3
    int bm0   = mt << 8;
    int batch = bm0 >> 13;
    int srow0 = bm0 & 8191;
    int bn0   = nt << 8;
    const __hip_bfloat16* xb = Xbf + (size_t)batch * XBATCH;

    int t    = threadIdx.x;
    int lane = t & 63;
    int wid  = t >> 6;            // 0..7
    int wr = wid >> 2, wc = wid & 3;
    int frr = lane & 15, q = lane >> 4;
    int swz = (frr & 7) << 4;

    // fragment read elem offsets (row pitch 64 elems = 128B)
    int aRd[2][4][2], bRd[4][2];
#pragma unroll
    for (int h = 0; h < 2; h++)
#pragma unroll
        for (int m = 0; m < 4; m++) {
            int row = wr * 128 + h * 64 + m * 16 + frr;
#pragma unroll
            for (int ks = 0; ks < 2; ks++)
                aRd[h][m][ks] = row * 64 + (((ks * 64 + (q << 4)) ^ swz) >> 1);
        }
#pragma unroll
    for (int n = 0; n < 4; n++) {
        int row = wc * 64 + n * 16 + frr;
#pragma unroll
        for (int ks = 0; ks < 2; ks++)
            bRd[n][ks] = row * 64 + (((ks * 64 + (q << 4)) ^ swz) >> 1);
    }

    // staging precompute (per thread, 2 chunks per half):
    int srcA[2], dstA[2], srcB[2], dstB[2];
#pragma unroll
    for (int ld = 0; ld < 2; ld++) {
        int u  = ld * 512 + t;
        int rr = u >> 3;
        int c  = u & 7;
        int growA = (rr < 64) ? rr : rr + 64;           // HF=0 quadrant rows
        dstA[ld] = growA * 8 + c;
        srcA[ld] = growA * 1024 + ((c ^ (growA & 7)) * 8);
        dstB[ld] = rr * 8 + c;
        srcB[ld] = rr * 4096 + ((c ^ (rr & 7)) * 8);
    }

    f32x4 acc[2][4][4];
#pragma unroll
    for (int h = 0; h < 2; h++)
#pragma unroll
        for (int m = 0; m < 4; m++)
#pragma unroll
            for (int n = 0; n < 4; n++) acc[h][m][n] = (f32x4){0.f, 0.f, 0.f, 0.f};

#define STAGEA(T, HF) do {                                                    \
        int tap_ = (T) >> 4;                                                  \
        int d0_  = ((T) & 15) << 6;                                           \
        int pA_  = ((T) & 1) << 15;                                           \
        const __hip_bfloat16* xT_ =                                           \
            xb + (size_t)(srow0 + 3 - tap_) * 1024 + d0_ + (HF) * 65536;      \
        _Pragma("unroll")                                                     \
        for (int ld = 0; ld < 2; ld++)                                        \
            async16(xT_ + srcA[ld], &LS[pA_ + (dstA[ld] + (HF) * 512) * 8]);  \
    } while (0)

#define STAGEB(T, HF) do {                                                    \
        int pA_  = ((T) & 1) << 15;                                           \
        const __hip_bfloat16* bT_ =                                           \
            Kt + (((size_t)(bn0 + (HF) * 128)) << 12) + (T) * 64;             \
        _Pragma("unroll")                                                     \
        for (int ld = 0; ld < 2; ld++)                                        \
            async16(bT_ + srcB[ld],                                           \
                    &LS[pA_ + 16384 + (dstB[ld] + (HF) * 1024) * 8]);         \
    } while (0)

    short8 bfr[4];

#define RD_A(H, KS, P) do {                                                   \
        _Pragma("unroll")                                                     \
        for (int m = 0; m < 4; m++)                                           \
            af[m] = *reinterpret_cast<const short8*>(                         \
                &LS[((P) << 15) + aRd[H][m][KS]]);                            \
    } while (0)

#define RD_B(KS, P) do {                                                      \
        _Pragma("unroll")                                                     \
        for (int n = 0; n < 4; n++)                                           \
            bfr[n] = *reinterpret_cast<const short8*>(                        \
                &LS[((P) << 15) + 16384 + bRd[n][KS]]);                       \
    } while (0)

#define MFMA16(H) do {                                                        \
        _Pragma("unroll")                                                     \
        for (int m = 0; m < 4; m++)                                           \
            _Pragma("unroll")                                                 \
            for (int n = 0; n < 4; n++)                                       \
                acc[H][m][n] = __builtin_amdgcn_mfma_f32_16x16x32_bf16(       \
                    af[m], bfr[n], acc[H][m][n], 0, 0, 0);                    \
    } while (0)

#define BARW(WAIT) do {                                                       \
        if ((WAIT) == 4) asm volatile("s_waitcnt vmcnt(4)" ::: "memory");     \
        else if ((WAIT) == 2) asm volatile("s_waitcnt vmcnt(2)" ::: "memory");\
        else if ((WAIT) == 0) asm volatile("s_waitcnt vmcnt(0)" ::: "memory");\
        __builtin_amdgcn_s_barrier();                                         \
        asm volatile("" ::: "memory");                                        \
    } while (0)

    // single-quadrant phase: [wait]+barrier -> reads -> stage -> 16 MFMA
#define PH(P, H, KS, RB, WAIT, STGSTMT) do {                                  \
        BARW(WAIT);                                                           \
        short8 af[4];                                                         \
        RD_A(H, KS, P);                                                       \
        if (RB) RD_B(KS, P);                                                  \
        STGSTMT;                                                              \
        MFMA16(H);                                                            \
    } while (0)

    // merged phase: (h1,ks0) + (h0,ks1) under ONE barrier
#define PH2(P, STGa, STGb) do {                                               \
        BARW(-1);                                                             \
        short8 af[4];                                                         \
        RD_A(1, 0, P);                                                        \
        STGa;                                                                 \
        MFMA16(1);          /* h1ks0 with bfr from ks0 */                     \
        RD_A(0, 1, P);                                                        \
        RD_B(1, P);                                                           \
        STGb;                                                                 \
        MFMA16(0);          /* h0ks1 with fresh bfr */                        \
    } while (0)

    // prologue: T0 both halves, T1 half0 (12 loads in flight)
    STAGEA(0, 0); STAGEB(0, 0);
    STAGEA(0, 1); STAGEB(0, 1);
    STAGEA(1, 0); STAGEB(1, 0);

    for (int I = 0; I < 31; ++I) {
        int T1 = 2 * I + 1, T2 = 2 * I + 2, T3 = 2 * I + 3;
        PH (0, 0, 0, 1,  4, STAGEA(T1, 1));          // P1
        PH2(0, STAGEB(T1, 1), ;);                    // P2 = h1ks0 + h0ks1
        PH (0, 1, 1, 0, -1, STAGEA(T2, 0));          // P3
        PH (1, 0, 0, 1,  2, STAGEB(T2, 0));          // P4
        PH2(1, STAGEA(T2, 1), STAGEB(T2, 1));        // P5
        PH (1, 1, 1, 0, -1, { STAGEA(T3, 0); STAGEB(T3, 0); });  // P6
    }
    // tail: tiles 62 (buf0) and 63 (buf1)
    PH (0, 0, 0, 1,  4, STAGEA(63, 1));
    PH2(0, STAGEB(63, 1), ;);
    PH (0, 1, 1, 0, -1, ;);
    PH (1, 0, 0, 1,  0, ;);                          // vmcnt(0): 63 landed
    PH2(1, ;, ;);
    PH (1, 1, 1, 0, -1, ;);

    // epilogue: C/D layout col=lane&15, row=(lane>>4)*4+j  [m89]
    int fr   = lane & 15;
    int rowg = (lane >> 4) << 2;
#pragma unroll
    for (int n = 0; n < 4; n++) {
        int gc = bn0 + wc * 64 + n * 16 + fr;
        float bsum = biases[gc] + biases[1024 + gc] + biases[2048 + gc] + biases[3072 + gc];
#pragma unroll
        for (int h = 0; h < 2; h++)
#pragma unroll
            for (int m = 0; m < 4; m++) {
                size_t gr = (size_t)(bm0 + wr * 128 + h * 64 + m * 16 + rowg);
#pragma unroll
                for (int j = 0; j < 4; j++) {
                    out[(gr + j) * 1024 + gc] = acc[h][m][n][j] + bsum;
                }
            }
    }
#undef STAGEA
#undef STAGEB
#undef RD_A
#undef RD_B
#undef MFMA16
#undef BARW
#undef PH
#undef PH2
}

// ---------------------------------------------------------------------------
// Fallback: plain fp32 (no workspace needed), correct but slow
// ---------------------------------------------------------------------------
__global__ void fallback_conv(const float* __restrict__ x, const float* __restrict__ kern,
                              const float* __restrict__ biases, float* __restrict__ out) {
    __shared__ float xs[1024];
    int row = blockIdx.x;
    int f = (blockIdx.y << 8) + threadIdx.x;
    int batch = row >> 13, s = row & 8191;
    const float* xb = x + (((size_t)batch << 13) << 10);
    float acc = 0.f;
    for (int tap = 0; tap < 4; tap++) {
        int ss = s - tap;
        __syncthreads();
        for (int i = threadIdx.x; i < 1024; i += 256)
            xs[i] = (ss >= 0) ? xb[((size_t)ss << 10) + i] : 0.f;
        __syncthreads();
        const float* kp = kern + ((size_t)tap << 20) + f;
        float a = 0.f;
        for (int d = 0; d < 1024; d++) a += xs[d] * kp[(size_t)d << 10];
        acc += a + biases[(tap << 10) + f];
    }
    out[((size_t)row << 10) + f] = acc;
}

extern "C" void kernel_launch(void* const* d_in, const int* in_sizes, int n_in,
                              void* d_out, int out_size, void* d_ws, size_t ws_size,
                              hipStream_t stream) {
    const float* x      = (const float*)d_in[0];
    const float* kern   = (const float*)d_in[1];
    const float* biases = (const float*)d_in[2];
    float* out = (float*)d_out;

    const size_t xbf_bytes = (size_t)4 * XBATCH * sizeof(__hip_bfloat16); // 67.1 MB
    const size_t kt_bytes  = (size_t)4096 * 1024 * sizeof(__hip_bfloat16); // 8.4 MB

    if (ws_size >= xbf_bytes + kt_bytes) {
        __hip_bfloat16* Xbf = (__hip_bfloat16*)d_ws;
        __hip_bfloat16* Kt  = (__hip_bfloat16*)((char*)d_ws + xbf_bytes);
        prepass_fused<<<6144, 256, 0, stream>>>(x, Xbf, kern, Kt);
        altconv_gemm18<<<512, 512, 0, stream>>>(Xbf, Kt, biases, out);
    } else {
        fallback_conv<<<dim3(32768, 4), 256, 0, stream>>>(x, kern, biases, out);
    }
}